// Round 14
// baseline (293.646 us; speedup 1.0000x reference)
//
#include <hip/hip_runtime.h>

#define H_  12
#define S_  3136
#define D_  768
#define NP_ 196
#define CHT 13          // stats: k-tiles per chunk (4*13=52 >= 49)
#define NCH 4
#define CHTE 7          // emit: k-tiles per chunk (7*7=49)
#define NCHE 7

typedef unsigned short u16;
typedef __bf16 bf16_t;
typedef bf16_t bf16x8 __attribute__((ext_vector_type(8)));
typedef float  f32x4  __attribute__((ext_vector_type(4)));
typedef u16    u16x4  __attribute__((ext_vector_type(4)));

typedef const __attribute__((address_space(1))) void* gas_ptr;
typedef __attribute__((address_space(3))) void* las_ptr;

__device__ __forceinline__ u16 f2bf(float f) {
    unsigned u = __float_as_uint(f);
    u += 0x7fffu + ((u >> 16) & 1u);   // RNE
    return (u16)(u >> 16);
}

__device__ __forceinline__ f32x4 mfma16(bf16x8 a, bf16x8 b, f32x4 c) {
    return __builtin_amdgcn_mfma_f32_16x16x32_bf16(a, b, c, 0, 0, 0);
}

__device__ __forceinline__ void gld16(const void* g, void* l) {
    __builtin_amdgcn_global_load_lds((gas_ptr)g, (las_ptr)l, 16, 0, 0);
}

// ---------------------------------------------------------------- convert
__global__ __launch_bounds__(256) void cvt7(
    const float* __restrict__ s0, const float* __restrict__ s1,
    const float* __restrict__ s2, const float* __restrict__ s3,
    const float* __restrict__ s4, const float* __restrict__ s5,
    const float* __restrict__ s6,
    u16* __restrict__ xb, u16* __restrict__ wb)
{
    const int which = blockIdx.y;
    const float* s; u16* d; int n;
    if (which < 3) {
        s = (which == 0) ? s0 : (which == 1) ? s1 : s2;
        d = xb + (size_t)which * 2408448; n = 2408448;
    } else {
        const int w = which - 3;
        s = (w == 0) ? s3 : (w == 1) ? s4 : (w == 2) ? s5 : s6;
        d = wb + (size_t)w * 589824; n = 589824;
    }
    const int i = (blockIdx.x * 256 + threadIdx.x) * 4;
    if (i >= n) return;
    const float4 v = *(const float4*)(s + i);
    u16x4 o = { f2bf(v.x), f2bf(v.y), f2bf(v.z), f2bf(v.w) };
    *(u16x4*)(d + i) = o;
}

// ---------------------------------------------------------------- QKV GEMM
__global__ __launch_bounds__(256) void qkv_gemm(
    const u16* __restrict__ Xall, const u16* __restrict__ Wall,
    const float* __restrict__ bq, const float* __restrict__ bk,
    const float* __restrict__ bv,
    float* __restrict__ yout, u16* __restrict__ qkbf, u16* __restrict__ vtbf)
{
    __shared__ u16 Alds[128][64];
    __shared__ u16 Blds[128][64];
    const int tid = threadIdx.x;
    const int z  = blockIdx.z;
    const int m0 = blockIdx.x * 128;
    const int n0 = blockIdx.y * 128;
    const u16* X = Xall + (size_t)z * (size_t)(S_ * D_);
    const u16* W = Wall + (size_t)z * (size_t)(D_ * D_);
    const int lane = tid & 63, wid = tid >> 6;
    const int l15 = lane & 15, lhi = lane >> 4;
    const int wm = wid >> 1, wn = wid & 1;

    const f32x4 zf = {0.f, 0.f, 0.f, 0.f};
    f32x4 acc[4][4];
#pragma unroll
    for (int mi = 0; mi < 4; ++mi)
#pragma unroll
        for (int ni = 0; ni < 4; ++ni) acc[mi][ni] = zf;

    for (int kt = 0; kt < 12; ++kt) {
        const int k0 = kt * 64;
#pragma unroll
        for (int it = 0; it < 4; ++it) {
            const int e   = it * 256 + tid;
            const int row = e >> 3;
            const int col = (e & 7) << 3;
            const int lbase = __builtin_amdgcn_readfirstlane((it * 256 + (tid & 192)) << 3);
            int ar = m0 + row; if (ar > S_ - 1) ar = S_ - 1;
            gld16(X + (size_t)ar * D_ + k0 + col, &Alds[0][0] + lbase);
            gld16(W + (size_t)(n0 + row) * D_ + k0 + col, &Blds[0][0] + lbase);
        }
        __syncthreads();
#pragma unroll
        for (int ks = 0; ks < 2; ++ks) {
            bf16x8 af[4], bfv[4];
#pragma unroll
            for (int mi = 0; mi < 4; ++mi)
                af[mi] = *(const bf16x8*)&Alds[wm*64 + mi*16 + l15][ks*32 + lhi*8];
#pragma unroll
            for (int ni = 0; ni < 4; ++ni)
                bfv[ni] = *(const bf16x8*)&Blds[wn*64 + ni*16 + l15][ks*32 + lhi*8];
#pragma unroll
            for (int mi = 0; mi < 4; ++mi)
#pragma unroll
                for (int ni = 0; ni < 4; ++ni)
                    acc[mi][ni] = mfma16(af[mi], bfv[ni], acc[mi][ni]);
        }
        __syncthreads();
    }

    const float* bias = (z == 0) ? bq : (z == 1) ? bk : bv;
    float* ysec = yout + (size_t)z * 2408448;
#pragma unroll
    for (int ni = 0; ni < 4; ++ni) {
        const int o = n0 + wn*64 + ni*16 + l15;
        const int head = o >> 6, dd = o & 63;
        const float bb = bias[o];
#pragma unroll
        for (int mi = 0; mi < 4; ++mi) {
            const int s0r = m0 + wm*64 + mi*16 + lhi*4;
            if (s0r >= S_) continue;
            const float y0 = acc[mi][ni][0] + bb;
            const float y1 = acc[mi][ni][1] + bb;
            const float y2 = acc[mi][ni][2] + bb;
            const float y3 = acc[mi][ni][3] + bb;
            float* yp = ysec + (size_t)head * (S_*64) + (size_t)s0r * 64 + dd;
            yp[0] = y0; yp[64] = y1; yp[128] = y2; yp[192] = y3;
            if (z < 2) {
                u16* qp = qkbf + (size_t)z * 2408448 + (size_t)head * (S_*64)
                        + (size_t)s0r * 64 + dd;
                qp[0] = f2bf(y0); qp[64] = f2bf(y1);
                qp[128] = f2bf(y2); qp[192] = f2bf(y3);
            } else {
                u16x4 pk = { f2bf(y0), f2bf(y1), f2bf(y2), f2bf(y3) };
                *(u16x4*)&vtbf[((size_t)head * 64 + dd) * S_ + s0r] = pk;
            }
        }
    }
}

// ---------------------------------------------------------------- stats+PV
// 256-row q-block, 4 q-sets per wave sharing each K/V load. PER-SET LDS
// strips: sets' QK->exp->pack->PV chains are independent (no ds-order
// coupling), so the scheduler can overlap set j+1's MFMAs with set j's
// LDS/PV tail.
__global__ __launch_bounds__(256, 2) void attn_stats(
    const u16* __restrict__ qh, const u16* __restrict__ kh,
    const u16* __restrict__ vt,
    float* __restrict__ lsum, float* __restrict__ Opart)
{
    __shared__ u16 P_lds[4][4][16][72];   // [wave][set][row][col]
    const int tid = threadIdx.x;
    const int wid = tid >> 6, lane = tid & 63;
    const int l15 = lane & 15, lhi = lane >> 4;
    const int h  = blockIdx.x;
    const int qt = blockIdx.y;
    const int c  = blockIdx.z;
    const int q0 = qt << 8;
    const int lastrow = min(q0 + 255, S_ - 1);
    const int Lmax = (lastrow / NP_ + 1) * NP_;
    const int kt0  = c * CHT;
    if (kt0 * 64 >= Lmax) return;
    const int ktend = min(kt0 + CHT, (Lmax + 63) >> 6);

    bf16x8 qv0[4], qv1[4];
    int lim[4]; bool have[4];
#pragma unroll
    for (int js = 0; js < 4; ++js) {
        const int qs0 = q0 + js*64;
        have[js] = (qs0 < S_);
        const int qs = have[js] ? (qs0 + wid*16 + l15) : (S_ - 1);
        const u16* qb = qh + ((size_t)h * S_ + qs) * 64 + lhi*8;
        qv0[js] = *(const bf16x8*)(qb);
        qv1[js] = *(const bf16x8*)(qb + 32);
        lim[js] = have[js] ? ((qs / NP_ + 1) * NP_) : 0;
    }

    const u16* khh = kh + (size_t)h * S_ * 64;
    const u16* vth = vt + (size_t)h * 64 * S_;
    const f32x4 zf = {0.f, 0.f, 0.f, 0.f};
    f32x4 ov[4][4];
#pragma unroll
    for (int js = 0; js < 4; ++js)
#pragma unroll
        for (int ni = 0; ni < 4; ++ni) ov[js][ni] = zf;
    float ssum[4] = {0.f, 0.f, 0.f, 0.f};

    for (int kt = kt0; kt < ktend; ++kt) {
        const int k0 = kt << 6;
        // shared K + V fragments for all 4 q-sets
        const u16* kb = khh + (size_t)(k0 + l15) * 64 + lhi * 8;
        bf16x8 ka0[4], ka1[4], vv0[4], vv1[4];
#pragma unroll
        for (int ni = 0; ni < 4; ++ni) {
            ka0[ni] = *(const bf16x8*)(kb + ni * 1024);
            ka1[ni] = *(const bf16x8*)(kb + ni * 1024 + 32);
        }
        const u16* vb = vth + (size_t)l15 * S_ + k0 + lhi*8;
#pragma unroll
        for (int ni = 0; ni < 4; ++ni) {
            vv0[ni] = *(const bf16x8*)(vb + (size_t)(ni*16) * S_);
            vv1[ni] = *(const bf16x8*)(vb + (size_t)(ni*16) * S_ + 32);
        }
#pragma unroll
        for (int js = 0; js < 4; ++js) {
            if (!have[js]) continue;
            f32x4 sc[4];
#pragma unroll
            for (int ni = 0; ni < 4; ++ni) {
                sc[ni] = mfma16(ka0[ni], qv0[js], zf);
                sc[ni] = mfma16(ka1[ni], qv1[js], sc[ni]);
            }
#pragma unroll
            for (int ni = 0; ni < 4; ++ni) {
                const int kk = k0 + ni*16 + lhi*4;
                u16x4 pb;
#pragma unroll
                for (int r = 0; r < 4; ++r) {
                    const float e  = __expf(sc[ni][r] * 0.125f);
                    const float pe = (kk + r < lim[js]) ? e : 0.f;
                    ssum[js] += pe;
                    pb[r] = f2bf(pe);
                }
                *(u16x4*)&P_lds[wid][js][l15][ni*16 + lhi*4] = pb;
            }
#pragma unroll
            for (int ks = 0; ks < 2; ++ks) {
                const bf16x8 pa = *(const bf16x8*)&P_lds[wid][js][l15][ks*32 + lhi*8];
#pragma unroll
                for (int ni = 0; ni < 4; ++ni)
                    ov[js][ni] = mfma16(pa, ks ? vv1[ni] : vv0[ni], ov[js][ni]);
            }
        }
    }

#pragma unroll
    for (int js = 0; js < 4; ++js) {
        if (!have[js]) continue;
        float s = ssum[js];
        s += __shfl_xor(s, 16);
        s += __shfl_xor(s, 32);
        const int qs = q0 + js*64 + wid*16 + l15;
        if (lhi == 0) atomicAdd(&lsum[(size_t)h * S_ + qs], s);
        float* op = Opart + ((size_t)(c * H_ + h) * S_) * 64;
#pragma unroll
        for (int ni = 0; ni < 4; ++ni)
#pragma unroll
            for (int r = 0; r < 4; ++r)
                op[(size_t)(q0 + js*64 + wid*16 + lhi*4 + r) * 64 + ni*16 + l15]
                    = ov[js][ni][r];
    }
}

// ---------------------------------------------------------------- zero fill
__global__ __launch_bounds__(256) void attn_zero(
    float* __restrict__ attn)
{
    const int h  = blockIdx.x;
    const int qt = blockIdx.y;
    const int q0 = qt << 6;
    const int Lmax = ((q0 + 63) / NP_ + 1) * NP_;
    const int z0 = ((Lmax + 63) >> 6) << 6;
    const int nq = (S_ - z0) >> 2;          // quads per row
    if (nq <= 0) return;
    const f32x4 zf = {0.f, 0.f, 0.f, 0.f};
    float* base = attn + (size_t)h * S_ * S_ + (size_t)q0 * S_ + z0;
    const int tid = threadIdx.x;
    for (int row = 0; row < 64; ++row) {
        f32x4* rp = (f32x4*)(base + (size_t)row * S_);
        for (int c = tid; c < nq; c += 256) rp[c] = zf;
    }
}

// ---------------------------------------------------------------- emit
// 256-row q-block, 4 q-sets per K load; NO LDS staging — plain direct
// f32x4 stores (measured equal to LDS-staged, and independent across
// sets so their chains overlap).
__global__ __launch_bounds__(256, 4) void attn_emit(
    const u16* __restrict__ qh, const u16* __restrict__ kh,
    const float* __restrict__ lsum, float* __restrict__ attn)
{
    const int tid = threadIdx.x;
    const int wid = tid >> 6, lane = tid & 63;
    const int l15 = lane & 15, lhi = lane >> 4;
    const int h  = blockIdx.x;
    const int qt = blockIdx.y;
    const int c  = blockIdx.z;
    const int q0 = qt << 8;
    const int lastrow = min(q0 + 255, S_ - 1);
    const int Lmax = (lastrow / NP_ + 1) * NP_;
    const int nkt  = (Lmax + 63) >> 6;
    const int kt0  = c * CHTE;
    if (kt0 >= nkt) return;
    const int ktend = min(kt0 + CHTE, nkt);

    bf16x8 qv0[4], qv1[4];
    int lim[4]; bool have[4]; float rl[4];
#pragma unroll
    for (int js = 0; js < 4; ++js) {
        const int qs0 = q0 + js*64;
        have[js] = (qs0 < S_);
        const int qs = have[js] ? (qs0 + wid*16 + l15) : (S_ - 1);
        const u16* qb = qh + ((size_t)h * S_ + qs) * 64 + lhi*8;
        qv0[js] = *(const bf16x8*)(qb);
        qv1[js] = *(const bf16x8*)(qb + 32);
        lim[js] = have[js] ? ((qs / NP_ + 1) * NP_) : 0;
        rl[js]  = have[js] ? (1.0f / lsum[(size_t)h * S_ + qs]) : 0.f;
    }

    const u16* khh = kh + (size_t)h * S_ * 64;
    const f32x4 zf = {0.f, 0.f, 0.f, 0.f};

    for (int kt = kt0; kt < ktend; ++kt) {
        const int k0 = kt << 6;
        const u16* kb = khh + (size_t)(k0 + l15) * 64 + lhi * 8;
        bf16x8 ka0[4], ka1[4];
#pragma unroll
        for (int ni = 0; ni < 4; ++ni) {
            ka0[ni] = *(const bf16x8*)(kb + ni * 1024);
            ka1[ni] = *(const bf16x8*)(kb + ni * 1024 + 32);
        }
#pragma unroll
        for (int js = 0; js < 4; ++js) {
            if (!have[js]) continue;
            f32x4 sc[4];
#pragma unroll
            for (int ni = 0; ni < 4; ++ni) {
                sc[ni] = mfma16(ka0[ni], qv0[js], zf);
                sc[ni] = mfma16(ka1[ni], qv1[js], sc[ni]);
            }
            const int qs = q0 + js*64 + wid*16 + l15;
            float* prow = attn + (size_t)h * S_ * S_ + (size_t)qs * S_;
#pragma unroll
            for (int ni = 0; ni < 4; ++ni) {
                const int kk = k0 + ni*16 + lhi*4;
                f32x4 pv;
#pragma unroll
                for (int r = 0; r < 4; ++r) {
                    const float e = __expf(sc[ni][r] * 0.125f) * rl[js];
                    pv[r] = (kk + r < lim[js]) ? e : 0.f;
                }
                *(f32x4*)(prow + kk) = pv;
            }
        }
    }
}

// ---------------------------------------------------------------- O cvt
__global__ __launch_bounds__(256) void o_cvt(
    const float* __restrict__ Opart, const float* __restrict__ lsum,
    u16* __restrict__ oh)
{
    const int i = blockIdx.x * 256 + threadIdx.x;   // over 12*3136*16 quads
    const int h  = i / (S_ * 16);
    const int rm = i - h * (S_ * 16);
    const int s  = rm >> 4;
    const int d  = (rm & 15) << 2;
    const int qblk0 = (s >> 8) << 8;
    const int last  = min(qblk0 + 255, S_ - 1);
    const int Lmax  = (last / NP_ + 1) * NP_;
    const int nact  = (Lmax + (CHT*64 - 1)) / (CHT*64);
    const float rl = 1.0f / lsum[(size_t)h * S_ + s];
    f32x4 acc = {0.f, 0.f, 0.f, 0.f};
    for (int c = 0; c < nact; ++c) {
        const f32x4 v = *(const f32x4*)&Opart[((size_t)(c * H_ + h) * S_ + s) * 64 + d];
        acc += v;
    }
    u16x4 o = { f2bf(acc[0] * rl), f2bf(acc[1] * rl),
                f2bf(acc[2] * rl), f2bf(acc[3] * rl) };
    *(u16x4*)&oh[(size_t)s * D_ + h * 64 + d] = o;
}

// ---------------------------------------------------------------- out proj
__global__ __launch_bounds__(256) void out_gemm(
    const u16* __restrict__ A, const u16* __restrict__ W,
    const float* __restrict__ bo, float* __restrict__ out)
{
    __shared__ u16 Alds[128][64];
    __shared__ u16 Blds[128][64];
    const int tid = threadIdx.x;
    const int m0 = blockIdx.x * 128;
    const int n0 = blockIdx.y * 128;
    const int lane = tid & 63, wid = tid >> 6;
    const int l15 = lane & 15, lhi = lane >> 4;
    const int wm = wid >> 1, wn = wid & 1;

    const f32x4 zf = {0.f, 0.f, 0.f, 0.f};
    f32x4 acc[4][4];
#pragma unroll
    for (int mi = 0; mi < 4; ++mi)
#pragma unroll
        for (int ni = 0; ni < 4; ++ni) acc[mi][ni] = zf;

    for (int kt = 0; kt < 12; ++kt) {
        const int k0 = kt * 64;
#pragma unroll
        for (int it = 0; it < 4; ++it) {
            const int e   = it * 256 + tid;
            const int row = e >> 3;
            const int col = (e & 7) << 3;
            const int lbase = __builtin_amdgcn_readfirstlane((it * 256 + (tid & 192)) << 3);
            int ar = m0 + row; if (ar > S_ - 1) ar = S_ - 1;
            gld16(A + (size_t)ar * D_ + k0 + col, &Alds[0][0] + lbase);
            gld16(W + (size_t)(n0 + row) * D_ + k0 + col, &Blds[0][0] + lbase);
        }
        __syncthreads();
#pragma unroll
        for (int ks = 0; ks < 2; ++ks) {
            bf16x8 af[4], bfv[4];
#pragma unroll
            for (int mi = 0; mi < 4; ++mi)
                af[mi] = *(const bf16x8*)&Alds[wm*64 + mi*16 + l15][ks*32 + lhi*8];
#pragma unroll
            for (int ni = 0; ni < 4; ++ni)
                bfv[ni] = *(const bf16x8*)&Blds[wn*64 + ni*16 + l15][ks*32 + lhi*8];
#pragma unroll
            for (int mi = 0; mi < 4; ++mi)
#pragma unroll
                for (int ni = 0; ni < 4; ++ni)
                    acc[mi][ni] = mfma16(af[mi], bfv[ni], acc[mi][ni]);
        }
        __syncthreads();
    }

#pragma unroll
    for (int ni = 0; ni < 4; ++ni) {
        const int o = n0 + wn*64 + ni*16 + l15;
        const float bb = bo[o];
#pragma unroll
        for (int mi = 0; mi < 4; ++mi) {
            const int s0r = m0 + wm*64 + mi*16 + lhi*4;
            if (s0r >= S_) continue;
            float* yp = out + (size_t)s0r * D_ + o;
            yp[0]       = acc[mi][ni][0] + bb;
            yp[D_]      = acc[mi][ni][1] + bb;
            yp[2 * D_]  = acc[mi][ni][2] + bb;
            yp[3 * D_]  = acc[mi][ni][3] + bb;
        }
    }
}

// ---------------------------------------------------------------- launcher
extern "C" void kernel_launch(void* const* d_in, const int* in_sizes, int n_in,
                              void* d_out, int out_size, void* d_ws, size_t ws_size,
                              hipStream_t stream) {
    const float* query = (const float*)d_in[0];
    const float* key_  = (const float*)d_in[1];
    const float* value = (const float*)d_in[2];
    const float* bq = (const float*)d_in[4];
    const float* bk = (const float*)d_in[6];
    const float* bv = (const float*)d_in[8];
    const float* bo = (const float*)d_in[10];

    float* out    = (float*)d_out;
    float* qkvh_f = out;                 // qh|kh|vh [h][s][64] x3
    float* attn_f = out + 7225344;       // [h][s][s]
    float* out_f  = out + 125239296;     // [s][768]

    char* ws = (char*)d_ws;
    u16* x_bf  = (u16*)(ws + 0);          // 3 x S*768 bf16
    u16* w_bf  = (u16*)(ws + 14450688);   // 4 x 768*768 bf16 (q,k,v,o)
    u16* qk_bf = (u16*)(ws + 19169280);   // qh_bf | kh_bf
    u16* vt_bf = (u16*)(ws + 28803072);   // [h][64][s]
    u16* oh_bf = (u16*)(ws + 33619968);   // [s][768]
    float* l_f = (float*)(ws + 38436864); // [h][s] denominators
    float* O_p = (float*)(ws + 38587392); // 4 x [h][s][64] fp32 partials

    (void)hipMemsetAsync(l_f, 0, (size_t)H_ * S_ * 4, stream);

    cvt7<<<dim3(2352, 7), 256, 0, stream>>>(query, key_, value,
        (const float*)d_in[3], (const float*)d_in[5],
        (const float*)d_in[7], (const float*)d_in[9], x_bf, w_bf);
    qkv_gemm<<<dim3(25, 6, 3), 256, 0, stream>>>(x_bf, w_bf, bq, bk, bv,
                                                 qkvh_f, qk_bf, vt_bf);
    attn_zero<<<dim3(12, 49), 256, 0, stream>>>(attn_f);
    attn_stats<<<dim3(12, 13, NCH), 256, 0, stream>>>(qk_bf,
        qk_bf + 2408448, vt_bf, l_f, O_p);
    attn_emit<<<dim3(12, 13, NCHE), 256, 0, stream>>>(qk_bf,
        qk_bf + 2408448, l_f, attn_f);
    o_cvt<<<dim3(2352), 256, 0, stream>>>(O_p, l_f, oh_bf);
    out_gemm<<<dim3(25, 6), 256, 0, stream>>>(oh_bf, w_bf + 3 * 589824, bo, out_f);
}

// Round 15
// 281.811 us; speedup vs baseline: 1.0420x; 1.0420x over previous
//
#include <hip/hip_runtime.h>

#define H_  12
#define S_  3136
#define D_  768
#define NP_ 196
#define CHT 13          // stats: k-tiles per chunk (4*13=52 >= 49)
#define NCH 4
#define CHTE 7          // emit: k-tiles per chunk (7*7=49)
#define NCHE 7

typedef unsigned short u16;
typedef __bf16 bf16_t;
typedef bf16_t bf16x8 __attribute__((ext_vector_type(8)));
typedef float  f32x4  __attribute__((ext_vector_type(4)));
typedef u16    u16x4  __attribute__((ext_vector_type(4)));

typedef const __attribute__((address_space(1))) void* gas_ptr;
typedef __attribute__((address_space(3))) void* las_ptr;

__device__ __forceinline__ u16 f2bf(float f) {
    unsigned u = __float_as_uint(f);
    u += 0x7fffu + ((u >> 16) & 1u);   // RNE
    return (u16)(u >> 16);
}

__device__ __forceinline__ f32x4 mfma16(bf16x8 a, bf16x8 b, f32x4 c) {
    return __builtin_amdgcn_mfma_f32_16x16x32_bf16(a, b, c, 0, 0, 0);
}

__device__ __forceinline__ void gld16(const void* g, void* l) {
    __builtin_amdgcn_global_load_lds((gas_ptr)g, (las_ptr)l, 16, 0, 0);
}

// ---------------------------------------------------------------- convert
__global__ __launch_bounds__(256) void cvt7(
    const float* __restrict__ s0, const float* __restrict__ s1,
    const float* __restrict__ s2, const float* __restrict__ s3,
    const float* __restrict__ s4, const float* __restrict__ s5,
    const float* __restrict__ s6,
    u16* __restrict__ xb, u16* __restrict__ wb)
{
    const int which = blockIdx.y;
    const float* s; u16* d; int n;
    if (which < 3) {
        s = (which == 0) ? s0 : (which == 1) ? s1 : s2;
        d = xb + (size_t)which * 2408448; n = 2408448;
    } else {
        const int w = which - 3;
        s = (w == 0) ? s3 : (w == 1) ? s4 : (w == 2) ? s5 : s6;
        d = wb + (size_t)w * 589824; n = 589824;
    }
    const int i = (blockIdx.x * 256 + threadIdx.x) * 4;
    if (i >= n) return;
    const float4 v = *(const float4*)(s + i);
    u16x4 o = { f2bf(v.x), f2bf(v.y), f2bf(v.z), f2bf(v.w) };
    *(u16x4*)(d + i) = o;
}

// ---------------------------------------------------------------- QKV GEMM
__global__ __launch_bounds__(256) void qkv_gemm(
    const u16* __restrict__ Xall, const u16* __restrict__ Wall,
    const float* __restrict__ bq, const float* __restrict__ bk,
    const float* __restrict__ bv,
    float* __restrict__ yout, u16* __restrict__ qkbf, u16* __restrict__ vtbf)
{
    __shared__ u16 Alds[128][64];
    __shared__ u16 Blds[128][64];
    const int tid = threadIdx.x;
    const int z  = blockIdx.z;
    const int m0 = blockIdx.x * 128;
    const int n0 = blockIdx.y * 128;
    const u16* X = Xall + (size_t)z * (size_t)(S_ * D_);
    const u16* W = Wall + (size_t)z * (size_t)(D_ * D_);
    const int lane = tid & 63, wid = tid >> 6;
    const int l15 = lane & 15, lhi = lane >> 4;
    const int wm = wid >> 1, wn = wid & 1;

    const f32x4 zf = {0.f, 0.f, 0.f, 0.f};
    f32x4 acc[4][4];
#pragma unroll
    for (int mi = 0; mi < 4; ++mi)
#pragma unroll
        for (int ni = 0; ni < 4; ++ni) acc[mi][ni] = zf;

    for (int kt = 0; kt < 12; ++kt) {
        const int k0 = kt * 64;
#pragma unroll
        for (int it = 0; it < 4; ++it) {
            const int e   = it * 256 + tid;
            const int row = e >> 3;
            const int col = (e & 7) << 3;
            const int lbase = __builtin_amdgcn_readfirstlane((it * 256 + (tid & 192)) << 3);
            int ar = m0 + row; if (ar > S_ - 1) ar = S_ - 1;
            gld16(X + (size_t)ar * D_ + k0 + col, &Alds[0][0] + lbase);
            gld16(W + (size_t)(n0 + row) * D_ + k0 + col, &Blds[0][0] + lbase);
        }
        __syncthreads();
#pragma unroll
        for (int ks = 0; ks < 2; ++ks) {
            bf16x8 af[4], bfv[4];
#pragma unroll
            for (int mi = 0; mi < 4; ++mi)
                af[mi] = *(const bf16x8*)&Alds[wm*64 + mi*16 + l15][ks*32 + lhi*8];
#pragma unroll
            for (int ni = 0; ni < 4; ++ni)
                bfv[ni] = *(const bf16x8*)&Blds[wn*64 + ni*16 + l15][ks*32 + lhi*8];
#pragma unroll
            for (int mi = 0; mi < 4; ++mi)
#pragma unroll
                for (int ni = 0; ni < 4; ++ni)
                    acc[mi][ni] = mfma16(af[mi], bfv[ni], acc[mi][ni]);
        }
        __syncthreads();
    }

    const float* bias = (z == 0) ? bq : (z == 1) ? bk : bv;
    float* ysec = yout + (size_t)z * 2408448;
#pragma unroll
    for (int ni = 0; ni < 4; ++ni) {
        const int o = n0 + wn*64 + ni*16 + l15;
        const int head = o >> 6, dd = o & 63;
        const float bb = bias[o];
#pragma unroll
        for (int mi = 0; mi < 4; ++mi) {
            const int s0r = m0 + wm*64 + mi*16 + lhi*4;
            if (s0r >= S_) continue;
            const float y0 = acc[mi][ni][0] + bb;
            const float y1 = acc[mi][ni][1] + bb;
            const float y2 = acc[mi][ni][2] + bb;
            const float y3 = acc[mi][ni][3] + bb;
            float* yp = ysec + (size_t)head * (S_*64) + (size_t)s0r * 64 + dd;
            yp[0] = y0; yp[64] = y1; yp[128] = y2; yp[192] = y3;
            if (z < 2) {
                u16* qp = qkbf + (size_t)z * 2408448 + (size_t)head * (S_*64)
                        + (size_t)s0r * 64 + dd;
                qp[0] = f2bf(y0); qp[64] = f2bf(y1);
                qp[128] = f2bf(y2); qp[192] = f2bf(y3);
            } else {
                u16x4 pk = { f2bf(y0), f2bf(y1), f2bf(y2), f2bf(y3) };
                *(u16x4*)&vtbf[((size_t)head * 64 + dd) * S_ + s0r] = pk;
            }
        }
    }
}

// ---------------------------------------------------------------- stats+PV
// r13 + ONE change: PER-SET LDS strips, so the 4 q-sets'
// QK->exp->pack->PV chains have no wave-ordered ds WAR coupling.
__global__ __launch_bounds__(256, 2) void attn_stats(
    const u16* __restrict__ qh, const u16* __restrict__ kh,
    const u16* __restrict__ vt,
    float* __restrict__ lsum, float* __restrict__ Opart)
{
    __shared__ u16 P_lds[4][4][16][72];   // [wave][set][row][col]
    const int tid = threadIdx.x;
    const int wid = tid >> 6, lane = tid & 63;
    const int l15 = lane & 15, lhi = lane >> 4;
    const int h  = blockIdx.x;
    const int qt = blockIdx.y;
    const int c  = blockIdx.z;
    const int q0 = qt << 8;
    const int lastrow = min(q0 + 255, S_ - 1);
    const int Lmax = (lastrow / NP_ + 1) * NP_;
    const int kt0  = c * CHT;
    if (kt0 * 64 >= Lmax) return;
    const int ktend = min(kt0 + CHT, (Lmax + 63) >> 6);

    bf16x8 qv0[4], qv1[4];
    int lim[4]; bool have[4];
#pragma unroll
    for (int js = 0; js < 4; ++js) {
        const int qs0 = q0 + js*64;
        have[js] = (qs0 < S_);
        const int qs = have[js] ? (qs0 + wid*16 + l15) : (S_ - 1);
        const u16* qb = qh + ((size_t)h * S_ + qs) * 64 + lhi*8;
        qv0[js] = *(const bf16x8*)(qb);
        qv1[js] = *(const bf16x8*)(qb + 32);
        lim[js] = have[js] ? ((qs / NP_ + 1) * NP_) : 0;
    }

    const u16* khh = kh + (size_t)h * S_ * 64;
    const u16* vth = vt + (size_t)h * 64 * S_;
    const f32x4 zf = {0.f, 0.f, 0.f, 0.f};
    f32x4 ov[4][4];
#pragma unroll
    for (int js = 0; js < 4; ++js)
#pragma unroll
        for (int ni = 0; ni < 4; ++ni) ov[js][ni] = zf;
    float ssum[4] = {0.f, 0.f, 0.f, 0.f};

    for (int kt = kt0; kt < ktend; ++kt) {
        const int k0 = kt << 6;
        // shared K + V fragments for all 4 q-sets
        const u16* kb = khh + (size_t)(k0 + l15) * 64 + lhi * 8;
        bf16x8 ka0[4], ka1[4], vv0[4], vv1[4];
#pragma unroll
        for (int ni = 0; ni < 4; ++ni) {
            ka0[ni] = *(const bf16x8*)(kb + ni * 1024);
            ka1[ni] = *(const bf16x8*)(kb + ni * 1024 + 32);
        }
        const u16* vb = vth + (size_t)l15 * S_ + k0 + lhi*8;
#pragma unroll
        for (int ni = 0; ni < 4; ++ni) {
            vv0[ni] = *(const bf16x8*)(vb + (size_t)(ni*16) * S_);
            vv1[ni] = *(const bf16x8*)(vb + (size_t)(ni*16) * S_ + 32);
        }
#pragma unroll
        for (int js = 0; js < 4; ++js) {
            if (!have[js]) continue;
            f32x4 sc[4];
#pragma unroll
            for (int ni = 0; ni < 4; ++ni) {
                sc[ni] = mfma16(ka0[ni], qv0[js], zf);
                sc[ni] = mfma16(ka1[ni], qv1[js], sc[ni]);
            }
#pragma unroll
            for (int ni = 0; ni < 4; ++ni) {
                const int kk = k0 + ni*16 + lhi*4;
                u16x4 pb;
#pragma unroll
                for (int r = 0; r < 4; ++r) {
                    const float e  = __expf(sc[ni][r] * 0.125f);
                    const float pe = (kk + r < lim[js]) ? e : 0.f;
                    ssum[js] += pe;
                    pb[r] = f2bf(pe);
                }
                *(u16x4*)&P_lds[wid][js][l15][ni*16 + lhi*4] = pb;
            }
#pragma unroll
            for (int ks = 0; ks < 2; ++ks) {
                const bf16x8 pa = *(const bf16x8*)&P_lds[wid][js][l15][ks*32 + lhi*8];
#pragma unroll
                for (int ni = 0; ni < 4; ++ni)
                    ov[js][ni] = mfma16(pa, ks ? vv1[ni] : vv0[ni], ov[js][ni]);
            }
        }
    }

#pragma unroll
    for (int js = 0; js < 4; ++js) {
        if (!have[js]) continue;
        float s = ssum[js];
        s += __shfl_xor(s, 16);
        s += __shfl_xor(s, 32);
        const int qs = q0 + js*64 + wid*16 + l15;
        if (lhi == 0) atomicAdd(&lsum[(size_t)h * S_ + qs], s);
        float* op = Opart + ((size_t)(c * H_ + h) * S_) * 64;
#pragma unroll
        for (int ni = 0; ni < 4; ++ni)
#pragma unroll
            for (int r = 0; r < 4; ++r)
                op[(size_t)(q0 + js*64 + wid*16 + lhi*4 + r) * 64 + ni*16 + l15]
                    = ov[js][ni][r];
    }
}

// ---------------------------------------------------------------- zero fill
__global__ __launch_bounds__(256) void attn_zero(
    float* __restrict__ attn)
{
    const int h  = blockIdx.x;
    const int qt = blockIdx.y;
    const int q0 = qt << 6;
    const int Lmax = ((q0 + 63) / NP_ + 1) * NP_;
    const int z0 = ((Lmax + 63) >> 6) << 6;
    const int nq = (S_ - z0) >> 2;          // quads per row
    if (nq <= 0) return;
    const f32x4 zf = {0.f, 0.f, 0.f, 0.f};
    float* base = attn + (size_t)h * S_ * S_ + (size_t)q0 * S_ + z0;
    const int tid = threadIdx.x;
    for (int row = 0; row < 64; ++row) {
        f32x4* rp = (f32x4*)(base + (size_t)row * S_);
        for (int c = tid; c < nq; c += 256) rp[c] = zf;
    }
}

// ---------------------------------------------------------------- emit
// r13-exact: 256-row q-block, 4 q-sets per K load; LDS-staged
// row-contiguous 256B stores.
__global__ __launch_bounds__(256, 4) void attn_emit(
    const u16* __restrict__ qh, const u16* __restrict__ kh,
    const float* __restrict__ lsum, float* __restrict__ attn)
{
    __shared__ float Pf[4][16][72];    // per-wave strip, reused across sets
    const int tid = threadIdx.x;
    const int wid = tid >> 6, lane = tid & 63;
    const int l15 = lane & 15, lhi = lane >> 4;
    const int h  = blockIdx.x;
    const int qt = blockIdx.y;
    const int c  = blockIdx.z;
    const int q0 = qt << 8;
    const int lastrow = min(q0 + 255, S_ - 1);
    const int Lmax = (lastrow / NP_ + 1) * NP_;
    const int nkt  = (Lmax + 63) >> 6;
    const int kt0  = c * CHTE;
    if (kt0 >= nkt) return;
    const int ktend = min(kt0 + CHTE, nkt);

    bf16x8 qv0[4], qv1[4];
    int lim[4]; bool have[4]; float rl[4];
#pragma unroll
    for (int js = 0; js < 4; ++js) {
        const int qs0 = q0 + js*64;
        have[js] = (qs0 < S_);
        const int qs = have[js] ? (qs0 + wid*16 + l15) : (S_ - 1);
        const u16* qb = qh + ((size_t)h * S_ + qs) * 64 + lhi*8;
        qv0[js] = *(const bf16x8*)(qb);
        qv1[js] = *(const bf16x8*)(qb + 32);
        lim[js] = have[js] ? ((qs / NP_ + 1) * NP_) : 0;
        rl[js]  = have[js] ? (1.0f / lsum[(size_t)h * S_ + qs]) : 0.f;
    }

    const int srow = lane >> 4;          // 0..3
    const int scol = (lane & 15) << 2;   // 0..60
    float* pbase0 = attn + (size_t)h * S_ * S_ + (size_t)(q0 + wid*16) * S_;

    const u16* khh = kh + (size_t)h * S_ * 64;
    const f32x4 zf = {0.f, 0.f, 0.f, 0.f};

    for (int kt = kt0; kt < ktend; ++kt) {
        const int k0 = kt << 6;
        const u16* kb = khh + (size_t)(k0 + l15) * 64 + lhi * 8;
        bf16x8 ka0[4], ka1[4];
#pragma unroll
        for (int ni = 0; ni < 4; ++ni) {
            ka0[ni] = *(const bf16x8*)(kb + ni * 1024);
            ka1[ni] = *(const bf16x8*)(kb + ni * 1024 + 32);
        }
#pragma unroll
        for (int js = 0; js < 4; ++js) {
            if (!have[js]) continue;
            f32x4 sc[4];
#pragma unroll
            for (int ni = 0; ni < 4; ++ni) {
                sc[ni] = mfma16(ka0[ni], qv0[js], zf);
                sc[ni] = mfma16(ka1[ni], qv1[js], sc[ni]);
            }
#pragma unroll
            for (int ni = 0; ni < 4; ++ni) {
                const int kk = k0 + ni*16 + lhi*4;
                f32x4 pv;
#pragma unroll
                for (int r = 0; r < 4; ++r) {
                    const float e = __expf(sc[ni][r] * 0.125f) * rl[js];
                    pv[r] = (kk + r < lim[js]) ? e : 0.f;
                }
                *(f32x4*)&Pf[wid][l15][ni*16 + lhi*4] = pv;
            }
            float* pbase = pbase0 + (size_t)(js * 64) * S_;
#pragma unroll
            for (int it = 0; it < 4; ++it) {
                const int row = it*4 + srow;
                const f32x4 v = *(const f32x4*)&Pf[wid][row][scol];
                *(f32x4*)(pbase + (size_t)row * S_ + k0 + scol) = v;
            }
        }
    }
}

// ---------------------------------------------------------------- O cvt
__global__ __launch_bounds__(256) void o_cvt(
    const float* __restrict__ Opart, const float* __restrict__ lsum,
    u16* __restrict__ oh)
{
    const int i = blockIdx.x * 256 + threadIdx.x;   // over 12*3136*16 quads
    const int h  = i / (S_ * 16);
    const int rm = i - h * (S_ * 16);
    const int s  = rm >> 4;
    const int d  = (rm & 15) << 2;
    const int qblk0 = (s >> 8) << 8;
    const int last  = min(qblk0 + 255, S_ - 1);
    const int Lmax  = (last / NP_ + 1) * NP_;
    const int nact  = (Lmax + (CHT*64 - 1)) / (CHT*64);
    const float rl = 1.0f / lsum[(size_t)h * S_ + s];
    f32x4 acc = {0.f, 0.f, 0.f, 0.f};
    for (int c = 0; c < nact; ++c) {
        const f32x4 v = *(const f32x4*)&Opart[((size_t)(c * H_ + h) * S_ + s) * 64 + d];
        acc += v;
    }
    u16x4 o = { f2bf(acc[0] * rl), f2bf(acc[1] * rl),
                f2bf(acc[2] * rl), f2bf(acc[3] * rl) };
    *(u16x4*)&oh[(size_t)s * D_ + h * 64 + d] = o;
}

// ---------------------------------------------------------------- out proj
__global__ __launch_bounds__(256) void out_gemm(
    const u16* __restrict__ A, const u16* __restrict__ W,
    const float* __restrict__ bo, float* __restrict__ out)
{
    __shared__ u16 Alds[128][64];
    __shared__ u16 Blds[128][64];
    const int tid = threadIdx.x;
    const int m0 = blockIdx.x * 128;
    const int n0 = blockIdx.y * 128;
    const int lane = tid & 63, wid = tid >> 6;
    const int l15 = lane & 15, lhi = lane >> 4;
    const int wm = wid >> 1, wn = wid & 1;

    const f32x4 zf = {0.f, 0.f, 0.f, 0.f};
    f32x4 acc[4][4];
#pragma unroll
    for (int mi = 0; mi < 4; ++mi)
#pragma unroll
        for (int ni = 0; ni < 4; ++ni) acc[mi][ni] = zf;

    for (int kt = 0; kt < 12; ++kt) {
        const int k0 = kt * 64;
#pragma unroll
        for (int it = 0; it < 4; ++it) {
            const int e   = it * 256 + tid;
            const int row = e >> 3;
            const int col = (e & 7) << 3;
            const int lbase = __builtin_amdgcn_readfirstlane((it * 256 + (tid & 192)) << 3);
            int ar = m0 + row; if (ar > S_ - 1) ar = S_ - 1;
            gld16(A + (size_t)ar * D_ + k0 + col, &Alds[0][0] + lbase);
            gld16(W + (size_t)(n0 + row) * D_ + k0 + col, &Blds[0][0] + lbase);
        }
        __syncthreads();
#pragma unroll
        for (int ks = 0; ks < 2; ++ks) {
            bf16x8 af[4], bfv[4];
#pragma unroll
            for (int mi = 0; mi < 4; ++mi)
                af[mi] = *(const bf16x8*)&Alds[wm*64 + mi*16 + l15][ks*32 + lhi*8];
#pragma unroll
            for (int ni = 0; ni < 4; ++ni)
                bfv[ni] = *(const bf16x8*)&Blds[wn*64 + ni*16 + l15][ks*32 + lhi*8];
#pragma unroll
            for (int mi = 0; mi < 4; ++mi)
#pragma unroll
                for (int ni = 0; ni < 4; ++ni)
                    acc[mi][ni] = mfma16(af[mi], bfv[ni], acc[mi][ni]);
        }
        __syncthreads();
    }

#pragma unroll
    for (int ni = 0; ni < 4; ++ni) {
        const int o = n0 + wn*64 + ni*16 + l15;
        const float bb = bo[o];
#pragma unroll
        for (int mi = 0; mi < 4; ++mi) {
            const int s0r = m0 + wm*64 + mi*16 + lhi*4;
            if (s0r >= S_) continue;
            float* yp = out + (size_t)s0r * D_ + o;
            yp[0]       = acc[mi][ni][0] + bb;
            yp[D_]      = acc[mi][ni][1] + bb;
            yp[2 * D_]  = acc[mi][ni][2] + bb;
            yp[3 * D_]  = acc[mi][ni][3] + bb;
        }
    }
}

// ---------------------------------------------------------------- launcher
extern "C" void kernel_launch(void* const* d_in, const int* in_sizes, int n_in,
                              void* d_out, int out_size, void* d_ws, size_t ws_size,
                              hipStream_t stream) {
    const float* query = (const float*)d_in[0];
    const float* key_  = (const float*)d_in[1];
    const float* value = (const float*)d_in[2];
    const float* bq = (const float*)d_in[4];
    const float* bk = (const float*)d_in[6];
    const float* bv = (const float*)d_in[8];
    const float* bo = (const float*)d_in[10];

    float* out    = (float*)d_out;
    float* qkvh_f = out;                 // qh|kh|vh [h][s][64] x3
    float* attn_f = out + 7225344;       // [h][s][s]
    float* out_f  = out + 125239296;     // [s][768]

    char* ws = (char*)d_ws;
    u16* x_bf  = (u16*)(ws + 0);          // 3 x S*768 bf16
    u16* w_bf  = (u16*)(ws + 14450688);   // 4 x 768*768 bf16 (q,k,v,o)
    u16* qk_bf = (u16*)(ws + 19169280);   // qh_bf | kh_bf
    u16* vt_bf = (u16*)(ws + 28803072);   // [h][64][s]
    u16* oh_bf = (u16*)(ws + 33619968);   // [s][768]
    float* l_f = (float*)(ws + 38436864); // [h][s] denominators
    float* O_p = (float*)(ws + 38587392); // 4 x [h][s][64] fp32 partials

    (void)hipMemsetAsync(l_f, 0, (size_t)H_ * S_ * 4, stream);

    cvt7<<<dim3(2352, 7), 256, 0, stream>>>(query, key_, value,
        (const float*)d_in[3], (const float*)d_in[5],
        (const float*)d_in[7], (const float*)d_in[9], x_bf, w_bf);
    qkv_gemm<<<dim3(25, 6, 3), 256, 0, stream>>>(x_bf, w_bf, bq, bk, bv,
                                                 qkvh_f, qk_bf, vt_bf);
    attn_zero<<<dim3(12, 49), 256, 0, stream>>>(attn_f);
    attn_stats<<<dim3(12, 13, NCH), 256, 0, stream>>>(qk_bf,
        qk_bf + 2408448, vt_bf, l_f, O_p);
    attn_emit<<<dim3(12, 13, NCHE), 256, 0, stream>>>(qk_bf,
        qk_bf + 2408448, l_f, attn_f);
    o_cvt<<<dim3(2352), 256, 0, stream>>>(O_p, l_f, oh_bf);
    out_gemm<<<dim3(25, 6), 256, 0, stream>>>(oh_bf, w_bf + 3 * 589824, bo, out_f);
}

// Round 16
// 268.525 us; speedup vs baseline: 1.0936x; 1.0495x over previous
//
#include <hip/hip_runtime.h>

#define H_  12
#define S_  3136
#define D_  768
#define NP_ 196
#define CHT 13          // stats: k-tiles per chunk (4*13=52 >= 49)
#define NCH 4
#define CHTE 7          // emit: k-tiles per chunk (7*7=49)
#define NCHE 7

typedef unsigned short u16;
typedef __bf16 bf16_t;
typedef bf16_t bf16x8 __attribute__((ext_vector_type(8)));
typedef float  f32x4  __attribute__((ext_vector_type(4)));
typedef u16    u16x4  __attribute__((ext_vector_type(4)));

typedef const __attribute__((address_space(1))) void* gas_ptr;
typedef __attribute__((address_space(3))) void* las_ptr;

__device__ __forceinline__ u16 f2bf(float f) {
    unsigned u = __float_as_uint(f);
    u += 0x7fffu + ((u >> 16) & 1u);   // RNE
    return (u16)(u >> 16);
}

__device__ __forceinline__ f32x4 mfma16(bf16x8 a, bf16x8 b, f32x4 c) {
    return __builtin_amdgcn_mfma_f32_16x16x32_bf16(a, b, c, 0, 0, 0);
}

__device__ __forceinline__ void gld16(const void* g, void* l) {
    __builtin_amdgcn_global_load_lds((gas_ptr)g, (las_ptr)l, 16, 0, 0);
}

// ---------------------------------------------------------------- convert
__global__ __launch_bounds__(256) void cvt7(
    const float* __restrict__ s0, const float* __restrict__ s1,
    const float* __restrict__ s2, const float* __restrict__ s3,
    const float* __restrict__ s4, const float* __restrict__ s5,
    const float* __restrict__ s6,
    u16* __restrict__ xb, u16* __restrict__ wb)
{
    const int which = blockIdx.y;
    const float* s; u16* d; int n;
    if (which < 3) {
        s = (which == 0) ? s0 : (which == 1) ? s1 : s2;
        d = xb + (size_t)which * 2408448; n = 2408448;
    } else {
        const int w = which - 3;
        s = (w == 0) ? s3 : (w == 1) ? s4 : (w == 2) ? s5 : s6;
        d = wb + (size_t)w * 589824; n = 589824;
    }
    const int i = (blockIdx.x * 256 + threadIdx.x) * 4;
    if (i >= n) return;
    const float4 v = *(const float4*)(s + i);
    u16x4 o = { f2bf(v.x), f2bf(v.y), f2bf(v.z), f2bf(v.w) };
    *(u16x4*)(d + i) = o;
}

// ---------------------------------------------------------------- QKV GEMM
__global__ __launch_bounds__(256) void qkv_gemm(
    const u16* __restrict__ Xall, const u16* __restrict__ Wall,
    const float* __restrict__ bq, const float* __restrict__ bk,
    const float* __restrict__ bv,
    float* __restrict__ yout, u16* __restrict__ qkbf, u16* __restrict__ vtbf)
{
    __shared__ u16 Alds[128][64];
    __shared__ u16 Blds[128][64];
    const int tid = threadIdx.x;
    const int z  = blockIdx.z;
    const int m0 = blockIdx.x * 128;
    const int n0 = blockIdx.y * 128;
    const u16* X = Xall + (size_t)z * (size_t)(S_ * D_);
    const u16* W = Wall + (size_t)z * (size_t)(D_ * D_);
    const int lane = tid & 63, wid = tid >> 6;
    const int l15 = lane & 15, lhi = lane >> 4;
    const int wm = wid >> 1, wn = wid & 1;

    const f32x4 zf = {0.f, 0.f, 0.f, 0.f};
    f32x4 acc[4][4];
#pragma unroll
    for (int mi = 0; mi < 4; ++mi)
#pragma unroll
        for (int ni = 0; ni < 4; ++ni) acc[mi][ni] = zf;

    for (int kt = 0; kt < 12; ++kt) {
        const int k0 = kt * 64;
#pragma unroll
        for (int it = 0; it < 4; ++it) {
            const int e   = it * 256 + tid;
            const int row = e >> 3;
            const int col = (e & 7) << 3;
            const int lbase = __builtin_amdgcn_readfirstlane((it * 256 + (tid & 192)) << 3);
            int ar = m0 + row; if (ar > S_ - 1) ar = S_ - 1;
            gld16(X + (size_t)ar * D_ + k0 + col, &Alds[0][0] + lbase);
            gld16(W + (size_t)(n0 + row) * D_ + k0 + col, &Blds[0][0] + lbase);
        }
        __syncthreads();
#pragma unroll
        for (int ks = 0; ks < 2; ++ks) {
            bf16x8 af[4], bfv[4];
#pragma unroll
            for (int mi = 0; mi < 4; ++mi)
                af[mi] = *(const bf16x8*)&Alds[wm*64 + mi*16 + l15][ks*32 + lhi*8];
#pragma unroll
            for (int ni = 0; ni < 4; ++ni)
                bfv[ni] = *(const bf16x8*)&Blds[wn*64 + ni*16 + l15][ks*32 + lhi*8];
#pragma unroll
            for (int mi = 0; mi < 4; ++mi)
#pragma unroll
                for (int ni = 0; ni < 4; ++ni)
                    acc[mi][ni] = mfma16(af[mi], bfv[ni], acc[mi][ni]);
        }
        __syncthreads();
    }

    const float* bias = (z == 0) ? bq : (z == 1) ? bk : bv;
    float* ysec = yout + (size_t)z * 2408448;
#pragma unroll
    for (int ni = 0; ni < 4; ++ni) {
        const int o = n0 + wn*64 + ni*16 + l15;
        const int head = o >> 6, dd = o & 63;
        const float bb = bias[o];
#pragma unroll
        for (int mi = 0; mi < 4; ++mi) {
            const int s0r = m0 + wm*64 + mi*16 + lhi*4;
            if (s0r >= S_) continue;
            const float y0 = acc[mi][ni][0] + bb;
            const float y1 = acc[mi][ni][1] + bb;
            const float y2 = acc[mi][ni][2] + bb;
            const float y3 = acc[mi][ni][3] + bb;
            float* yp = ysec + (size_t)head * (S_*64) + (size_t)s0r * 64 + dd;
            yp[0] = y0; yp[64] = y1; yp[128] = y2; yp[192] = y3;
            if (z < 2) {
                u16* qp = qkbf + (size_t)z * 2408448 + (size_t)head * (S_*64)
                        + (size_t)s0r * 64 + dd;
                qp[0] = f2bf(y0); qp[64] = f2bf(y1);
                qp[128] = f2bf(y2); qp[192] = f2bf(y3);
            } else {
                u16x4 pk = { f2bf(y0), f2bf(y1), f2bf(y2), f2bf(y3) };
                *(u16x4*)&vtbf[((size_t)head * 64 + dd) * S_ + s0r] = pk;
            }
        }
    }
}

// ---------------------------------------------------------------- stats+PV
// r15-exact: 256-row q-block, 4 q-sets per K/V load, per-set LDS strips.
__global__ __launch_bounds__(256, 2) void attn_stats(
    const u16* __restrict__ qh, const u16* __restrict__ kh,
    const u16* __restrict__ vt,
    float* __restrict__ lsum, float* __restrict__ Opart)
{
    __shared__ u16 P_lds[4][4][16][72];   // [wave][set][row][col]
    const int tid = threadIdx.x;
    const int wid = tid >> 6, lane = tid & 63;
    const int l15 = lane & 15, lhi = lane >> 4;
    const int h  = blockIdx.x;
    const int qt = blockIdx.y;
    const int c  = blockIdx.z;
    const int q0 = qt << 8;
    const int lastrow = min(q0 + 255, S_ - 1);
    const int Lmax = (lastrow / NP_ + 1) * NP_;
    const int kt0  = c * CHT;
    if (kt0 * 64 >= Lmax) return;
    const int ktend = min(kt0 + CHT, (Lmax + 63) >> 6);

    bf16x8 qv0[4], qv1[4];
    int lim[4]; bool have[4];
#pragma unroll
    for (int js = 0; js < 4; ++js) {
        const int qs0 = q0 + js*64;
        have[js] = (qs0 < S_);
        const int qs = have[js] ? (qs0 + wid*16 + l15) : (S_ - 1);
        const u16* qb = qh + ((size_t)h * S_ + qs) * 64 + lhi*8;
        qv0[js] = *(const bf16x8*)(qb);
        qv1[js] = *(const bf16x8*)(qb + 32);
        lim[js] = have[js] ? ((qs / NP_ + 1) * NP_) : 0;
    }

    const u16* khh = kh + (size_t)h * S_ * 64;
    const u16* vth = vt + (size_t)h * 64 * S_;
    const f32x4 zf = {0.f, 0.f, 0.f, 0.f};
    f32x4 ov[4][4];
#pragma unroll
    for (int js = 0; js < 4; ++js)
#pragma unroll
        for (int ni = 0; ni < 4; ++ni) ov[js][ni] = zf;
    float ssum[4] = {0.f, 0.f, 0.f, 0.f};

    for (int kt = kt0; kt < ktend; ++kt) {
        const int k0 = kt << 6;
        // shared K + V fragments for all 4 q-sets
        const u16* kb = khh + (size_t)(k0 + l15) * 64 + lhi * 8;
        bf16x8 ka0[4], ka1[4], vv0[4], vv1[4];
#pragma unroll
        for (int ni = 0; ni < 4; ++ni) {
            ka0[ni] = *(const bf16x8*)(kb + ni * 1024);
            ka1[ni] = *(const bf16x8*)(kb + ni * 1024 + 32);
        }
        const u16* vb = vth + (size_t)l15 * S_ + k0 + lhi*8;
#pragma unroll
        for (int ni = 0; ni < 4; ++ni) {
            vv0[ni] = *(const bf16x8*)(vb + (size_t)(ni*16) * S_);
            vv1[ni] = *(const bf16x8*)(vb + (size_t)(ni*16) * S_ + 32);
        }
#pragma unroll
        for (int js = 0; js < 4; ++js) {
            if (!have[js]) continue;
            f32x4 sc[4];
#pragma unroll
            for (int ni = 0; ni < 4; ++ni) {
                sc[ni] = mfma16(ka0[ni], qv0[js], zf);
                sc[ni] = mfma16(ka1[ni], qv1[js], sc[ni]);
            }
#pragma unroll
            for (int ni = 0; ni < 4; ++ni) {
                const int kk = k0 + ni*16 + lhi*4;
                u16x4 pb;
#pragma unroll
                for (int r = 0; r < 4; ++r) {
                    const float e  = __expf(sc[ni][r] * 0.125f);
                    const float pe = (kk + r < lim[js]) ? e : 0.f;
                    ssum[js] += pe;
                    pb[r] = f2bf(pe);
                }
                *(u16x4*)&P_lds[wid][js][l15][ni*16 + lhi*4] = pb;
            }
#pragma unroll
            for (int ks = 0; ks < 2; ++ks) {
                const bf16x8 pa = *(const bf16x8*)&P_lds[wid][js][l15][ks*32 + lhi*8];
#pragma unroll
                for (int ni = 0; ni < 4; ++ni)
                    ov[js][ni] = mfma16(pa, ks ? vv1[ni] : vv0[ni], ov[js][ni]);
            }
        }
    }

#pragma unroll
    for (int js = 0; js < 4; ++js) {
        if (!have[js]) continue;
        float s = ssum[js];
        s += __shfl_xor(s, 16);
        s += __shfl_xor(s, 32);
        const int qs = q0 + js*64 + wid*16 + l15;
        if (lhi == 0) atomicAdd(&lsum[(size_t)h * S_ + qs], s);
        float* op = Opart + ((size_t)(c * H_ + h) * S_) * 64;
#pragma unroll
        for (int ni = 0; ni < 4; ++ni)
#pragma unroll
            for (int r = 0; r < 4; ++r)
                op[(size_t)(q0 + js*64 + wid*16 + lhi*4 + r) * 64 + ni*16 + l15]
                    = ov[js][ni][r];
    }
}

// ---------------------------------------------------------------- emit
// r15 emit + fused zero-fill: masked tiles (kt >= nkt) stream full-line
// zeros for the block's 256 rows instead of exiting — the zero work runs
// concurrently with the latency-bound compute chunks in ONE dispatch
// (attn_zero kernel deleted).
__global__ __launch_bounds__(256, 4) void attn_emit(
    const u16* __restrict__ qh, const u16* __restrict__ kh,
    const float* __restrict__ lsum, float* __restrict__ attn)
{
    __shared__ float Pf[4][16][72];    // per-wave strip, reused across sets
    const int tid = threadIdx.x;
    const int wid = tid >> 6, lane = tid & 63;
    const int l15 = lane & 15, lhi = lane >> 4;
    const int h  = blockIdx.x;
    const int qt = blockIdx.y;
    const int c  = blockIdx.z;
    const int q0 = qt << 8;
    const int lastrow = min(q0 + 255, S_ - 1);
    const int Lmax = (lastrow / NP_ + 1) * NP_;
    const int nkt  = (Lmax + 63) >> 6;
    const int kt0  = c * CHTE;
    const int ktend = min(kt0 + CHTE, 49);   // cover masked tiles too
    const int nrows = min(256, S_ - q0);

    bf16x8 qv0[4], qv1[4];
    int lim[4]; bool have[4]; float rl[4];
#pragma unroll
    for (int js = 0; js < 4; ++js) {
        const int qs0 = q0 + js*64;
        have[js] = (qs0 < S_);
        const int qs = have[js] ? (qs0 + wid*16 + l15) : (S_ - 1);
        const u16* qb = qh + ((size_t)h * S_ + qs) * 64 + lhi*8;
        qv0[js] = *(const bf16x8*)(qb);
        qv1[js] = *(const bf16x8*)(qb + 32);
        lim[js] = have[js] ? ((qs / NP_ + 1) * NP_) : 0;
        rl[js]  = have[js] ? (1.0f / lsum[(size_t)h * S_ + qs]) : 0.f;
    }

    const int srow = lane >> 4;          // 0..3
    const int scol = (lane & 15) << 2;   // 0..60
    float* pbase0 = attn + (size_t)h * S_ * S_ + (size_t)(q0 + wid*16) * S_;
    float* zbase  = attn + (size_t)h * S_ * S_ + (size_t)q0 * S_;
    const int zrow0 = tid >> 4;          // 0..15
    const int zcol  = (tid & 15) << 2;   // 0..60

    const u16* khh = kh + (size_t)h * S_ * 64;
    const f32x4 zf = {0.f, 0.f, 0.f, 0.f};

    for (int kt = kt0; kt < ktend; ++kt) {
        const int k0 = kt << 6;
        if (kt >= nkt) {
            // fused zero-fill: 256-row x 64-col tile, full-line stores
            float* zb = zbase + k0;
            for (int rr = zrow0; rr < nrows; rr += 16)
                *(f32x4*)(zb + (size_t)rr * S_ + zcol) = zf;
            continue;
        }
        const u16* kb = khh + (size_t)(k0 + l15) * 64 + lhi * 8;
        bf16x8 ka0[4], ka1[4];
#pragma unroll
        for (int ni = 0; ni < 4; ++ni) {
            ka0[ni] = *(const bf16x8*)(kb + ni * 1024);
            ka1[ni] = *(const bf16x8*)(kb + ni * 1024 + 32);
        }
#pragma unroll
        for (int js = 0; js < 4; ++js) {
            if (!have[js]) continue;
            f32x4 sc[4];
#pragma unroll
            for (int ni = 0; ni < 4; ++ni) {
                sc[ni] = mfma16(ka0[ni], qv0[js], zf);
                sc[ni] = mfma16(ka1[ni], qv1[js], sc[ni]);
            }
#pragma unroll
            for (int ni = 0; ni < 4; ++ni) {
                const int kk = k0 + ni*16 + lhi*4;
                f32x4 pv;
#pragma unroll
                for (int r = 0; r < 4; ++r) {
                    const float e = __expf(sc[ni][r] * 0.125f) * rl[js];
                    pv[r] = (kk + r < lim[js]) ? e : 0.f;
                }
                *(f32x4*)&Pf[wid][l15][ni*16 + lhi*4] = pv;
            }
            float* pbase = pbase0 + (size_t)(js * 64) * S_;
#pragma unroll
            for (int it = 0; it < 4; ++it) {
                const int row = it*4 + srow;
                const f32x4 v = *(const f32x4*)&Pf[wid][row][scol];
                *(f32x4*)(pbase + (size_t)row * S_ + k0 + scol) = v;
            }
        }
    }
}

// ---------------------------------------------------------------- O cvt
__global__ __launch_bounds__(256) void o_cvt(
    const float* __restrict__ Opart, const float* __restrict__ lsum,
    u16* __restrict__ oh)
{
    const int i = blockIdx.x * 256 + threadIdx.x;   // over 12*3136*16 quads
    const int h  = i / (S_ * 16);
    const int rm = i - h * (S_ * 16);
    const int s  = rm >> 4;
    const int d  = (rm & 15) << 2;
    const int qblk0 = (s >> 8) << 8;
    const int last  = min(qblk0 + 255, S_ - 1);
    const int Lmax  = (last / NP_ + 1) * NP_;
    const int nact  = (Lmax + (CHT*64 - 1)) / (CHT*64);
    const float rl = 1.0f / lsum[(size_t)h * S_ + s];
    f32x4 acc = {0.f, 0.f, 0.f, 0.f};
    for (int c = 0; c < nact; ++c) {
        const f32x4 v = *(const f32x4*)&Opart[((size_t)(c * H_ + h) * S_ + s) * 64 + d];
        acc += v;
    }
    u16x4 o = { f2bf(acc[0] * rl), f2bf(acc[1] * rl),
                f2bf(acc[2] * rl), f2bf(acc[3] * rl) };
    *(u16x4*)&oh[(size_t)s * D_ + h * 64 + d] = o;
}

// ---------------------------------------------------------------- out proj
__global__ __launch_bounds__(256) void out_gemm(
    const u16* __restrict__ A, const u16* __restrict__ W,
    const float* __restrict__ bo, float* __restrict__ out)
{
    __shared__ u16 Alds[128][64];
    __shared__ u16 Blds[128][64];
    const int tid = threadIdx.x;
    const int m0 = blockIdx.x * 128;
    const int n0 = blockIdx.y * 128;
    const int lane = tid & 63, wid = tid >> 6;
    const int l15 = lane & 15, lhi = lane >> 4;
    const int wm = wid >> 1, wn = wid & 1;

    const f32x4 zf = {0.f, 0.f, 0.f, 0.f};
    f32x4 acc[4][4];
#pragma unroll
    for (int mi = 0; mi < 4; ++mi)
#pragma unroll
        for (int ni = 0; ni < 4; ++ni) acc[mi][ni] = zf;

    for (int kt = 0; kt < 12; ++kt) {
        const int k0 = kt * 64;
#pragma unroll
        for (int it = 0; it < 4; ++it) {
            const int e   = it * 256 + tid;
            const int row = e >> 3;
            const int col = (e & 7) << 3;
            const int lbase = __builtin_amdgcn_readfirstlane((it * 256 + (tid & 192)) << 3);
            int ar = m0 + row; if (ar > S_ - 1) ar = S_ - 1;
            gld16(A + (size_t)ar * D_ + k0 + col, &Alds[0][0] + lbase);
            gld16(W + (size_t)(n0 + row) * D_ + k0 + col, &Blds[0][0] + lbase);
        }
        __syncthreads();
#pragma unroll
        for (int ks = 0; ks < 2; ++ks) {
            bf16x8 af[4], bfv[4];
#pragma unroll
            for (int mi = 0; mi < 4; ++mi)
                af[mi] = *(const bf16x8*)&Alds[wm*64 + mi*16 + l15][ks*32 + lhi*8];
#pragma unroll
            for (int ni = 0; ni < 4; ++ni)
                bfv[ni] = *(const bf16x8*)&Blds[wn*64 + ni*16 + l15][ks*32 + lhi*8];
#pragma unroll
            for (int mi = 0; mi < 4; ++mi)
#pragma unroll
                for (int ni = 0; ni < 4; ++ni)
                    acc[mi][ni] = mfma16(af[mi], bfv[ni], acc[mi][ni]);
        }
        __syncthreads();
    }

#pragma unroll
    for (int ni = 0; ni < 4; ++ni) {
        const int o = n0 + wn*64 + ni*16 + l15;
        const float bb = bo[o];
#pragma unroll
        for (int mi = 0; mi < 4; ++mi) {
            const int s0r = m0 + wm*64 + mi*16 + lhi*4;
            if (s0r >= S_) continue;
            float* yp = out + (size_t)s0r * D_ + o;
            yp[0]       = acc[mi][ni][0] + bb;
            yp[D_]      = acc[mi][ni][1] + bb;
            yp[2 * D_]  = acc[mi][ni][2] + bb;
            yp[3 * D_]  = acc[mi][ni][3] + bb;
        }
    }
}

// ---------------------------------------------------------------- launcher
extern "C" void kernel_launch(void* const* d_in, const int* in_sizes, int n_in,
                              void* d_out, int out_size, void* d_ws, size_t ws_size,
                              hipStream_t stream) {
    const float* query = (const float*)d_in[0];
    const float* key_  = (const float*)d_in[1];
    const float* value = (const float*)d_in[2];
    const float* bq = (const float*)d_in[4];
    const float* bk = (const float*)d_in[6];
    const float* bv = (const float*)d_in[8];
    const float* bo = (const float*)d_in[10];

    float* out    = (float*)d_out;
    float* qkvh_f = out;                 // qh|kh|vh [h][s][64] x3
    float* attn_f = out + 7225344;       // [h][s][s]
    float* out_f  = out + 125239296;     // [s][768]

    char* ws = (char*)d_ws;
    u16* x_bf  = (u16*)(ws + 0);          // 3 x S*768 bf16
    u16* w_bf  = (u16*)(ws + 14450688);   // 4 x 768*768 bf16 (q,k,v,o)
    u16* qk_bf = (u16*)(ws + 19169280);   // qh_bf | kh_bf
    u16* vt_bf = (u16*)(ws + 28803072);   // [h][64][s]
    u16* oh_bf = (u16*)(ws + 33619968);   // [s][768]
    float* l_f = (float*)(ws + 38436864); // [h][s] denominators
    float* O_p = (float*)(ws + 38587392); // 4 x [h][s][64] fp32 partials

    (void)hipMemsetAsync(l_f, 0, (size_t)H_ * S_ * 4, stream);

    cvt7<<<dim3(2352, 7), 256, 0, stream>>>(query, key_, value,
        (const float*)d_in[3], (const float*)d_in[5],
        (const float*)d_in[7], (const float*)d_in[9], x_bf, w_bf);
    qkv_gemm<<<dim3(25, 6, 3), 256, 0, stream>>>(x_bf, w_bf, bq, bk, bv,
                                                 qkvh_f, qk_bf, vt_bf);
    attn_stats<<<dim3(12, 13, NCH), 256, 0, stream>>>(qk_bf,
        qk_bf + 2408448, vt_bf, l_f, O_p);
    attn_emit<<<dim3(12, 13, NCHE), 256, 0, stream>>>(qk_bf,
        qk_bf + 2408448, l_f, attn_f);
    o_cvt<<<dim3(2352), 256, 0, stream>>>(O_p, l_f, oh_bf);
    out_gemm<<<dim3(25, 6), 256, 0, stream>>>(oh_bf, w_bf + 3 * 589824, bo, out_f);
}